// Round 10
// baseline (532.585 us; speedup 1.0000x reference)
//
#include <hip/hip_runtime.h>
#include <hip/hip_fp16.h>
#include <type_traits>

#define C 128

typedef _Float16 half8 __attribute__((ext_vector_type(8)));
typedef float f32x4 __attribute__((ext_vector_type(4)));

// ---------------------------------------------------------------------------
// zero counters: cnt[N] and degbins[256]
__global__ __launch_bounds__(256) void k_zero(int* __restrict__ cnt,
                                              int* __restrict__ degbins, int N) {
    int i = blockIdx.x * 256 + threadIdx.x;
    if (i < N) cnt[i] = 0;
    if (i < 256) degbins[i] = 0;
}

// in-degree histogram + per-edge rank: rank[e] = old count of dst[e]
__global__ __launch_bounds__(256) void k_histr(const int* __restrict__ dst,
                                               int* __restrict__ cnt,
                                               unsigned short* __restrict__ rank,
                                               int E) {
    int e = blockIdx.x * 256 + threadIdx.x;
    if (e < E) rank[e] = (unsigned short)atomicAdd(&cnt[dst[e]], 1);
}

// scan step 1: per-block (256-chunk) sums of cnt
__global__ __launch_bounds__(256) void k_scan1(const int* __restrict__ cnt,
                                               int* __restrict__ partials, int N) {
    __shared__ int sdata[256];
    int i = blockIdx.x * 256 + threadIdx.x;
    sdata[threadIdx.x] = (i < N) ? cnt[i] : 0;
    __syncthreads();
    for (int s = 128; s > 0; s >>= 1) {
        if (threadIdx.x < s) sdata[threadIdx.x] += sdata[threadIdx.x + s];
        __syncthreads();
    }
    if (threadIdx.x == 0) partials[blockIdx.x] = sdata[0];
}

// scan step 2: exclusive scan of the block partials (parallel, nb <= 256)
__global__ __launch_bounds__(256) void k_scan2(int* __restrict__ partials, int nb) {
    __shared__ int s[2][256];
    int t = threadIdx.x;
    if (nb <= 256) {
        int v = (t < nb) ? partials[t] : 0;
        int buf = 0;
        s[0][t] = v;
        __syncthreads();
        for (int off = 1; off < 256; off <<= 1) {
            int x = s[buf][t];
            if (t >= off) x += s[buf][t - off];
            s[buf ^ 1][t] = x;
            buf ^= 1;
            __syncthreads();
        }
        if (t < nb) partials[t] = s[buf][t] - v;  // exclusive
    } else if (t == 0) {
        int run = 0;
        for (int b = 0; b < nb; ++b) { int v = partials[b]; partials[b] = run; run += v; }
    }
}

// scan step 3: rowptr (exclusive scan), dinv = rsqrt(deg), degree-bin histogram
__global__ __launch_bounds__(256) void k_scan3(const int* __restrict__ cnt,
                                               const int* __restrict__ partials,
                                               int* __restrict__ rowptr,
                                               float* __restrict__ dinv,
                                               int* __restrict__ degbins,
                                               int N, int E) {
    __shared__ int s[2][256];
    int i = blockIdx.x * 256 + threadIdx.x;
    int v = (i < N) ? cnt[i] : 0;
    int buf = 0;
    s[0][threadIdx.x] = v;
    __syncthreads();
    for (int off = 1; off < 256; off <<= 1) {
        int t = s[buf][threadIdx.x];
        if (threadIdx.x >= off) t += s[buf][threadIdx.x - off];
        s[buf ^ 1][threadIdx.x] = t;
        buf ^= 1;
        __syncthreads();
    }
    int incl = s[buf][threadIdx.x];
    int excl = incl - v + partials[blockIdx.x];
    if (i < N) {
        rowptr[i] = excl;
        dinv[i] = rsqrtf((float)v + 1.0f);
        int b = v > 255 ? 255 : v;
        atomicAdd(&degbins[b], 1);
    }
    if (i == 0) rowptr[N] = E;
}

// degree-bin exclusive scan (in place, 1 block) + zero degfill
__global__ __launch_bounds__(256) void k_degscan(int* __restrict__ degbins,
                                                 int* __restrict__ degfill) {
    __shared__ int s[2][256];
    int t = threadIdx.x;
    int v = degbins[t];
    int buf = 0;
    s[0][t] = v;
    __syncthreads();
    for (int off = 1; off < 256; off <<= 1) {
        int x = s[buf][t];
        if (t >= off) x += s[buf][t - off];
        s[buf ^ 1][t] = x;
        buf ^= 1;
        __syncthreads();
    }
    degbins[t] = s[buf][t] - v;  // exclusive
    degfill[t] = 0;
}

// build degree-sorted node permutation
__global__ __launch_bounds__(256) void k_permfill(const int* __restrict__ cnt,
                                                  const int* __restrict__ degbins,
                                                  int* __restrict__ degfill,
                                                  int* __restrict__ perm, int N) {
    int i = blockIdx.x * 256 + threadIdx.x;
    if (i >= N) return;
    int d = cnt[i];
    d = d > 255 ? 255 : d;
    int pos = degbins[d] + atomicAdd(&degfill[d], 1);
    perm[pos] = i;
}

// fill CSR columns (atomic-free): col[rowptr[dst]+rank] = src  (uint16)
__global__ __launch_bounds__(256) void k_fill2(const int* __restrict__ src,
                                               const int* __restrict__ dst,
                                               const unsigned short* __restrict__ rank,
                                               const int* __restrict__ rowptr,
                                               unsigned short* __restrict__ col, int E) {
    int e = blockIdx.x * 256 + threadIdx.x;
    if (e >= E) return;
    int pos = rowptr[dst[e]] + (int)rank[e];
    col[pos] = (unsigned short)src[e];
}

// ---------------------------------------------------------------------------
// Hs16 = fp16((X @ W) * dinv[row]) via split-precision f16 MFMA.
// TA=float: split X into hi+lo, 3 MFMAs. TA=_Float16: X exact in fp16, 2 MFMAs.
template <typename TA>
__global__ __launch_bounds__(256) void k_gemm_mfma(const TA* __restrict__ X,
                                                   const float* __restrict__ W,
                                                   const float* __restrict__ dinv,
                                                   _Float16* __restrict__ Hs16,
                                                   int M) {
    __shared__ _Float16 WtH[C * C];
    __shared__ _Float16 WtL[C * C];
    const int t = threadIdx.x;

    // stage W^T hi/lo, XOR-swizzling the 16B (8-half) chunk index with n&15
    for (int idx = t; idx < C * C; idx += 256) {
        int k = idx >> 7, n = idx & 127;
        float w = W[idx];
        _Float16 h = (_Float16)w;
        _Float16 l = (_Float16)(w - (float)h);
        int off = n * C + (((k >> 3) ^ (n & 15)) << 3) + (k & 7);
        WtH[off] = h;
        WtL[off] = l;
    }
    __syncthreads();

    const int wv = t >> 6, lane = t & 63;
    const int l15 = lane & 15, lg = lane >> 4;  // lg = k-group (0..3)
    const int rowA = blockIdx.x * 64 + wv * 16 + l15;
    const bool aok = rowA < M;
    const TA* xrow = X + (size_t)rowA * C;

    f32x4 acc[8];
#pragma unroll
    for (int i = 0; i < 8; ++i) acc[i] = (f32x4){0.f, 0.f, 0.f, 0.f};

#pragma unroll
    for (int ks = 0; ks < 4; ++ks) {
        const int k0 = ks * 32 + lg * 8;
        half8 ah = (half8)(_Float16)0;
        half8 al = (half8)(_Float16)0;
        if constexpr (std::is_same_v<TA, float>) {
            if (aok) {
                float4 x0 = *(const float4*)(xrow + k0);
                float4 x1 = *(const float4*)(xrow + k0 + 4);
                _Float16 h;
                h = (_Float16)x0.x; ah[0] = h; al[0] = (_Float16)(x0.x - (float)h);
                h = (_Float16)x0.y; ah[1] = h; al[1] = (_Float16)(x0.y - (float)h);
                h = (_Float16)x0.z; ah[2] = h; al[2] = (_Float16)(x0.z - (float)h);
                h = (_Float16)x0.w; ah[3] = h; al[3] = (_Float16)(x0.w - (float)h);
                h = (_Float16)x1.x; ah[4] = h; al[4] = (_Float16)(x1.x - (float)h);
                h = (_Float16)x1.y; ah[5] = h; al[5] = (_Float16)(x1.y - (float)h);
                h = (_Float16)x1.z; ah[6] = h; al[6] = (_Float16)(x1.z - (float)h);
                h = (_Float16)x1.w; ah[7] = h; al[7] = (_Float16)(x1.w - (float)h);
            }
        } else {
            if (aok) ah = *(const half8*)(xrow + k0);
        }
        const int chb = ks * 4 + lg;
#pragma unroll
        for (int ct = 0; ct < 8; ++ct) {
            const int n = ct * 16 + l15;
            const int off = n * C + ((chb ^ l15) << 3);
            half8 bh = *(const half8*)&WtH[off];
            half8 bl = *(const half8*)&WtL[off];
            acc[ct] = __builtin_amdgcn_mfma_f32_16x16x32_f16(ah, bh, acc[ct], 0, 0, 0);
            if constexpr (std::is_same_v<TA, float>)
                acc[ct] = __builtin_amdgcn_mfma_f32_16x16x32_f16(al, bh, acc[ct], 0, 0, 0);
            acc[ct] = __builtin_amdgcn_mfma_f32_16x16x32_f16(ah, bl, acc[ct], 0, 0, 0);
        }
    }

    // C layout: col = lane&15, row = (lane>>4)*4 + reg
    const int rowC = blockIdx.x * 64 + wv * 16 + lg * 4;
#pragma unroll
    for (int r = 0; r < 4; ++r) {
        int row = rowC + r;
        if (row >= M) continue;
        float s = dinv[row];
#pragma unroll
        for (int ct = 0; ct < 8; ++ct) {
            Hs16[(size_t)row * C + ct * 16 + l15] = (_Float16)(acc[ct][r] * s);
        }
    }
}

// ---------------------------------------------------------------------------
// fused aggregation, degree-sorted order. MODE 0: write fp16 layer output.
// MODE 1: fused classifier — out[node,0..9] = relu(h) . Wl + bl.
template <int MODE>
__global__ __launch_bounds__(256) void k_aggf(const _Float16* __restrict__ Hs16,
                                              const int* __restrict__ rowptr,
                                              const unsigned short* __restrict__ col,
                                              const int* __restrict__ perm,
                                              const float* __restrict__ dinv,
                                              const float* __restrict__ b,
                                              const float* __restrict__ Wl,
                                              const float* __restrict__ bl,
                                              void* __restrict__ OutP, int N) {
    __shared__ float wlds[(MODE == 1) ? C * 10 : 1];
    if (MODE == 1) {
        for (int i = threadIdx.x; i < C * 10; i += 256) wlds[i] = Wl[i];
        __syncthreads();
    }

    const int gid = blockIdx.x * 8 + (threadIdx.x >> 5);
    const int lane = threadIdx.x & 31;
    if (gid >= N) return;
    const int node = perm[gid];
    const uint2* __restrict__ H16 = (const uint2*)Hs16;  // row stride 32 uint2

    uint2 qs = H16[(size_t)node * 32 + lane];  // self (Hs already row-scaled)
    float2 sa = __half22float2(*(__half2*)&qs.x);
    float2 sb = __half22float2(*(__half2*)&qs.y);
    float4 acc = make_float4(sa.x, sa.y, sb.x, sb.y);

    const int e0 = rowptr[node], e1 = rowptr[node + 1];
    int j = e0;
    for (; j + 8 <= e1; j += 8) {
        uint2 q[8];
#pragma unroll
        for (int u = 0; u < 8; ++u) {
            int n = col[j + u];
            q[u] = H16[(size_t)n * 32 + lane];
        }
#pragma unroll
        for (int u = 0; u < 8; ++u) {
            float2 a = __half22float2(*(__half2*)&q[u].x);
            float2 c = __half22float2(*(__half2*)&q[u].y);
            acc.x += a.x; acc.y += a.y; acc.z += c.x; acc.w += c.y;
        }
    }
    for (; j + 4 <= e1; j += 4) {
        uint2 q[4];
#pragma unroll
        for (int u = 0; u < 4; ++u) {
            int n = col[j + u];
            q[u] = H16[(size_t)n * 32 + lane];
        }
#pragma unroll
        for (int u = 0; u < 4; ++u) {
            float2 a = __half22float2(*(__half2*)&q[u].x);
            float2 c = __half22float2(*(__half2*)&q[u].y);
            acc.x += a.x; acc.y += a.y; acc.z += c.x; acc.w += c.y;
        }
    }
    for (; j < e1; ++j) {
        int n = col[j];
        uint2 q = H16[(size_t)n * 32 + lane];
        float2 a = __half22float2(*(__half2*)&q.x);
        float2 c = __half22float2(*(__half2*)&q.y);
        acc.x += a.x; acc.y += a.y; acc.z += c.x; acc.w += c.y;
    }

    const float s = dinv[node];
    const float4 bb = *(const float4*)(b + lane * 4);
    float4 o;
    o.x = s * acc.x + bb.x; o.y = s * acc.y + bb.y;
    o.z = s * acc.z + bb.z; o.w = s * acc.w + bb.w;
    o.x = o.x > 0.f ? o.x : 0.f;
    o.y = o.y > 0.f ? o.y : 0.f;
    o.z = o.z > 0.f ? o.z : 0.f;
    o.w = o.w > 0.f ? o.w : 0.f;

    if (MODE == 0) {
        __half2 h01 = __floats2half2_rn(o.x, o.y);
        __half2 h23 = __floats2half2_rn(o.z, o.w);
        uint2 pk;
        pk.x = *(unsigned int*)&h01;
        pk.y = *(unsigned int*)&h23;
        ((uint2*)OutP)[(size_t)node * 32 + lane] = pk;
    } else {
        float p[10];
        const int c0 = lane * 4;
#pragma unroll
        for (int k = 0; k < 10; ++k) {
            p[k] = o.x * wlds[(c0 + 0) * 10 + k] + o.y * wlds[(c0 + 1) * 10 + k] +
                   o.z * wlds[(c0 + 2) * 10 + k] + o.w * wlds[(c0 + 3) * 10 + k];
        }
#pragma unroll
        for (int k = 0; k < 10; ++k) {
            float v = p[k];
            v += __shfl_xor(v, 1);
            v += __shfl_xor(v, 2);
            v += __shfl_xor(v, 4);
            v += __shfl_xor(v, 8);
            v += __shfl_xor(v, 16);
            p[k] = v;
        }
        if (lane == 0) {
            float* outp = (float*)OutP + (size_t)node * 10;
#pragma unroll
            for (int k = 0; k < 10; ++k) outp[k] = p[k] + bl[k];
        }
    }
}

// ---------------------------------------------------------------------------
extern "C" void kernel_launch(void* const* d_in, const int* in_sizes, int n_in,
                              void* d_out, int out_size, void* d_ws, size_t ws_size,
                              hipStream_t stream) {
    const float* x  = (const float*)d_in[0];
    const int*   ei = (const int*)d_in[1];
    const float* W1 = (const float*)d_in[2];
    const float* b1 = (const float*)d_in[3];
    const float* W2 = (const float*)d_in[4];
    const float* b2 = (const float*)d_in[5];
    const float* Wl = (const float*)d_in[6];
    const float* bl = (const float*)d_in[7];
    float* out = (float*)d_out;

    const int N = in_sizes[0] / C;   // 50000
    const int E = in_sizes[1] / 2;   // 800000
    const int* src = ei;
    const int* dst = ei + E;

    char* p = (char*)d_ws;
    _Float16* bufHs16 = (_Float16*)p;  p += (size_t)N * C * 2;
    _Float16* bufT16  = (_Float16*)p;  p += (size_t)N * C * 2;
    int*      cnt     = (int*)p;       p += (size_t)N * 4;
    int*      rowptr  = (int*)p;       p += (size_t)(N + 1) * 4;
    float*    dinv    = (float*)p;     p += (size_t)N * 4;
    int*      perm    = (int*)p;       p += (size_t)N * 4;
    int*      partials= (int*)p;       p += 1024;
    int*      degbins = (int*)p;       p += 1024;
    int*      degfill = (int*)p;       p += 1024;
    unsigned short* rank   = (unsigned short*)p;  p += (size_t)E * 2;
    unsigned short* colidx = (unsigned short*)p;

    const int gridN   = (N + 255) / 256;       // 196
    const int gridE   = (E + 255) / 256;       // 3125
    const int gridGemm = (N + 63) / 64;        // 782
    const int gridAgg = (N + 7) / 8;           // 6250

    // CSR build + degree-sorted permutation (once; shared by both layers)
    k_zero<<<gridN, 256, 0, stream>>>(cnt, degbins, N);
    k_histr<<<gridE, 256, 0, stream>>>(dst, cnt, rank, E);
    k_scan1<<<gridN, 256, 0, stream>>>(cnt, partials, N);
    k_scan2<<<1, 256, 0, stream>>>(partials, gridN);
    k_scan3<<<gridN, 256, 0, stream>>>(cnt, partials, rowptr, dinv, degbins, N, E);
    k_degscan<<<1, 256, 0, stream>>>(degbins, degfill);
    k_permfill<<<gridN, 256, 0, stream>>>(cnt, degbins, degfill, perm, N);
    k_fill2<<<gridE, 256, 0, stream>>>(src, dst, rank, rowptr, colidx, E);

    // layer 1
    k_gemm_mfma<float><<<gridGemm, 256, 0, stream>>>(x, W1, dinv, bufHs16, N);
    k_aggf<0><<<gridAgg, 256, 0, stream>>>(bufHs16, rowptr, colidx, perm, dinv,
                                           b1, nullptr, nullptr, bufT16, N);

    // layer 2
    k_gemm_mfma<_Float16><<<gridGemm, 256, 0, stream>>>(bufT16, W2, dinv, bufHs16, N);
    k_aggf<1><<<gridAgg, 256, 0, stream>>>(bufHs16, rowptr, colidx, perm, dinv,
                                           b2, Wl, bl, out, N);
}

// Round 16
// 252.954 us; speedup vs baseline: 2.1055x; 2.1055x over previous
//
#include <hip/hip_runtime.h>
#include <hip/hip_fp16.h>
#include <type_traits>

#define C 128

typedef _Float16 half8 __attribute__((ext_vector_type(8)));
typedef float f32x4 __attribute__((ext_vector_type(4)));

// ---------------------------------------------------------------------------
// zero the in-degree counters
__global__ __launch_bounds__(256) void k_zero(int* __restrict__ cnt, int N) {
    int i = blockIdx.x * 256 + threadIdx.x;
    if (i < N) cnt[i] = 0;
}

// in-degree histogram + per-edge rank: rank[e] = old count of dst[e]
__global__ __launch_bounds__(256) void k_histr(const int* __restrict__ dst,
                                               int* __restrict__ cnt,
                                               unsigned short* __restrict__ rank,
                                               int E) {
    int e = blockIdx.x * 256 + threadIdx.x;
    if (e < E) rank[e] = (unsigned short)atomicAdd(&cnt[dst[e]], 1);
}

// scan step 1: per-block (256-chunk) sums of cnt
__global__ __launch_bounds__(256) void k_scan1(const int* __restrict__ cnt,
                                               int* __restrict__ partials, int N) {
    __shared__ int sdata[256];
    int i = blockIdx.x * 256 + threadIdx.x;
    sdata[threadIdx.x] = (i < N) ? cnt[i] : 0;
    __syncthreads();
    for (int s = 128; s > 0; s >>= 1) {
        if (threadIdx.x < s) sdata[threadIdx.x] += sdata[threadIdx.x + s];
        __syncthreads();
    }
    if (threadIdx.x == 0) partials[blockIdx.x] = sdata[0];
}

// scan step 2: exclusive scan of the block partials (parallel, nb <= 256)
__global__ __launch_bounds__(256) void k_scan2(int* __restrict__ partials, int nb) {
    __shared__ int s[2][256];
    int t = threadIdx.x;
    if (nb <= 256) {
        int v = (t < nb) ? partials[t] : 0;
        int buf = 0;
        s[0][t] = v;
        __syncthreads();
        for (int off = 1; off < 256; off <<= 1) {
            int x = s[buf][t];
            if (t >= off) x += s[buf][t - off];
            s[buf ^ 1][t] = x;
            buf ^= 1;
            __syncthreads();
        }
        if (t < nb) partials[t] = s[buf][t] - v;  // exclusive
    } else if (t == 0) {
        int run = 0;
        for (int b = 0; b < nb; ++b) { int v = partials[b]; partials[b] = run; run += v; }
    }
}

// scan step 3: rowptr (exclusive scan) + dinv = rsqrt(deg), deg = cnt + 1
__global__ __launch_bounds__(256) void k_scan3(const int* __restrict__ cnt,
                                               const int* __restrict__ partials,
                                               int* __restrict__ rowptr,
                                               float* __restrict__ dinv,
                                               int N, int E) {
    __shared__ int s[2][256];
    int i = blockIdx.x * 256 + threadIdx.x;
    int v = (i < N) ? cnt[i] : 0;
    int buf = 0;
    s[0][threadIdx.x] = v;
    __syncthreads();
    for (int off = 1; off < 256; off <<= 1) {
        int t = s[buf][threadIdx.x];
        if (threadIdx.x >= off) t += s[buf][threadIdx.x - off];
        s[buf ^ 1][threadIdx.x] = t;
        buf ^= 1;
        __syncthreads();
    }
    int incl = s[buf][threadIdx.x];
    int excl = incl - v + partials[blockIdx.x];
    if (i < N) {
        rowptr[i] = excl;
        dinv[i] = rsqrtf((float)v + 1.0f);
    }
    if (i == 0) rowptr[N] = E;
}

// fill CSR columns (atomic-free): col[rowptr[dst]+rank] = src  (uint16)
__global__ __launch_bounds__(256) void k_fill2(const int* __restrict__ src,
                                               const int* __restrict__ dst,
                                               const unsigned short* __restrict__ rank,
                                               const int* __restrict__ rowptr,
                                               unsigned short* __restrict__ col, int E) {
    int e = blockIdx.x * 256 + threadIdx.x;
    if (e >= E) return;
    int pos = rowptr[dst[e]] + (int)rank[e];
    col[pos] = (unsigned short)src[e];
}

// ---------------------------------------------------------------------------
// Hs16 = fp16((X @ W) * dinv[row]) via split-precision f16 MFMA.
// TA=float: split X into hi+lo, 3 MFMAs. TA=_Float16: X exact in fp16, 2 MFMAs.
template <typename TA>
__global__ __launch_bounds__(256) void k_gemm_mfma(const TA* __restrict__ X,
                                                   const float* __restrict__ W,
                                                   const float* __restrict__ dinv,
                                                   _Float16* __restrict__ Hs16,
                                                   int M) {
    __shared__ _Float16 WtH[C * C];
    __shared__ _Float16 WtL[C * C];
    const int t = threadIdx.x;

    // stage W^T hi/lo, XOR-swizzling the 16B (8-half) chunk index with n&15
    for (int idx = t; idx < C * C; idx += 256) {
        int k = idx >> 7, n = idx & 127;
        float w = W[idx];
        _Float16 h = (_Float16)w;
        _Float16 l = (_Float16)(w - (float)h);
        int off = n * C + (((k >> 3) ^ (n & 15)) << 3) + (k & 7);
        WtH[off] = h;
        WtL[off] = l;
    }
    __syncthreads();

    const int wv = t >> 6, lane = t & 63;
    const int l15 = lane & 15, lg = lane >> 4;  // lg = k-group (0..3)
    const int rowA = blockIdx.x * 64 + wv * 16 + l15;
    const bool aok = rowA < M;
    const TA* xrow = X + (size_t)rowA * C;

    f32x4 acc[8];
#pragma unroll
    for (int i = 0; i < 8; ++i) acc[i] = (f32x4){0.f, 0.f, 0.f, 0.f};

#pragma unroll
    for (int ks = 0; ks < 4; ++ks) {
        const int k0 = ks * 32 + lg * 8;
        half8 ah = (half8)(_Float16)0;
        half8 al = (half8)(_Float16)0;
        if constexpr (std::is_same_v<TA, float>) {
            if (aok) {
                float4 x0 = *(const float4*)(xrow + k0);
                float4 x1 = *(const float4*)(xrow + k0 + 4);
                _Float16 h;
                h = (_Float16)x0.x; ah[0] = h; al[0] = (_Float16)(x0.x - (float)h);
                h = (_Float16)x0.y; ah[1] = h; al[1] = (_Float16)(x0.y - (float)h);
                h = (_Float16)x0.z; ah[2] = h; al[2] = (_Float16)(x0.z - (float)h);
                h = (_Float16)x0.w; ah[3] = h; al[3] = (_Float16)(x0.w - (float)h);
                h = (_Float16)x1.x; ah[4] = h; al[4] = (_Float16)(x1.x - (float)h);
                h = (_Float16)x1.y; ah[5] = h; al[5] = (_Float16)(x1.y - (float)h);
                h = (_Float16)x1.z; ah[6] = h; al[6] = (_Float16)(x1.z - (float)h);
                h = (_Float16)x1.w; ah[7] = h; al[7] = (_Float16)(x1.w - (float)h);
            }
        } else {
            if (aok) ah = *(const half8*)(xrow + k0);
        }
        const int chb = ks * 4 + lg;
#pragma unroll
        for (int ct = 0; ct < 8; ++ct) {
            const int n = ct * 16 + l15;
            const int off = n * C + ((chb ^ l15) << 3);
            half8 bh = *(const half8*)&WtH[off];
            half8 bl = *(const half8*)&WtL[off];
            acc[ct] = __builtin_amdgcn_mfma_f32_16x16x32_f16(ah, bh, acc[ct], 0, 0, 0);
            if constexpr (std::is_same_v<TA, float>)
                acc[ct] = __builtin_amdgcn_mfma_f32_16x16x32_f16(al, bh, acc[ct], 0, 0, 0);
            acc[ct] = __builtin_amdgcn_mfma_f32_16x16x32_f16(ah, bl, acc[ct], 0, 0, 0);
        }
    }

    // C layout: col = lane&15, row = (lane>>4)*4 + reg
    const int rowC = blockIdx.x * 64 + wv * 16 + lg * 4;
#pragma unroll
    for (int r = 0; r < 4; ++r) {
        int row = rowC + r;
        if (row >= M) continue;
        float s = dinv[row];
#pragma unroll
        for (int ct = 0; ct < 8; ++ct) {
            Hs16[(size_t)row * C + ct * 16 + l15] = (_Float16)(acc[ct][r] * s);
        }
    }
}

// ---------------------------------------------------------------------------
// fused aggregation. MODE 0: write fp16 layer output.
// MODE 1: fused classifier — out[node,0..9] = relu(h) . Wl + bl.
template <int MODE>
__global__ __launch_bounds__(256) void k_aggf(const _Float16* __restrict__ Hs16,
                                              const int* __restrict__ rowptr,
                                              const unsigned short* __restrict__ col,
                                              const float* __restrict__ dinv,
                                              const float* __restrict__ b,
                                              const float* __restrict__ Wl,
                                              const float* __restrict__ bl,
                                              void* __restrict__ OutP, int N) {
    __shared__ float wlds[(MODE == 1) ? C * 10 : 1];
    if (MODE == 1) {
        for (int i = threadIdx.x; i < C * 10; i += 256) wlds[i] = Wl[i];
        __syncthreads();
    }

    const int node = blockIdx.x * 8 + (threadIdx.x >> 5);
    const int lane = threadIdx.x & 31;
    if (node >= N) return;
    const uint2* __restrict__ H16 = (const uint2*)Hs16;  // row stride 32 uint2

    uint2 qs = H16[(size_t)node * 32 + lane];  // self (Hs already row-scaled)
    float2 sa = __half22float2(*(__half2*)&qs.x);
    float2 sb = __half22float2(*(__half2*)&qs.y);
    float4 acc = make_float4(sa.x, sa.y, sb.x, sb.y);

    const int e0 = rowptr[node], e1 = rowptr[node + 1];
    int j = e0;
    for (; j + 8 <= e1; j += 8) {
        uint2 q[8];
#pragma unroll
        for (int u = 0; u < 8; ++u) {
            int n = col[j + u];
            q[u] = H16[(size_t)n * 32 + lane];
        }
#pragma unroll
        for (int u = 0; u < 8; ++u) {
            float2 a = __half22float2(*(__half2*)&q[u].x);
            float2 c = __half22float2(*(__half2*)&q[u].y);
            acc.x += a.x; acc.y += a.y; acc.z += c.x; acc.w += c.y;
        }
    }
    for (; j + 4 <= e1; j += 4) {
        uint2 q[4];
#pragma unroll
        for (int u = 0; u < 4; ++u) {
            int n = col[j + u];
            q[u] = H16[(size_t)n * 32 + lane];
        }
#pragma unroll
        for (int u = 0; u < 4; ++u) {
            float2 a = __half22float2(*(__half2*)&q[u].x);
            float2 c = __half22float2(*(__half2*)&q[u].y);
            acc.x += a.x; acc.y += a.y; acc.z += c.x; acc.w += c.y;
        }
    }
    for (; j < e1; ++j) {
        int n = col[j];
        uint2 q = H16[(size_t)n * 32 + lane];
        float2 a = __half22float2(*(__half2*)&q.x);
        float2 c = __half22float2(*(__half2*)&q.y);
        acc.x += a.x; acc.y += a.y; acc.z += c.x; acc.w += c.y;
    }

    const float s = dinv[node];
    const float4 bb = *(const float4*)(b + lane * 4);
    float4 o;
    o.x = s * acc.x + bb.x; o.y = s * acc.y + bb.y;
    o.z = s * acc.z + bb.z; o.w = s * acc.w + bb.w;
    o.x = o.x > 0.f ? o.x : 0.f;
    o.y = o.y > 0.f ? o.y : 0.f;
    o.z = o.z > 0.f ? o.z : 0.f;
    o.w = o.w > 0.f ? o.w : 0.f;

    if (MODE == 0) {
        __half2 h01 = __floats2half2_rn(o.x, o.y);
        __half2 h23 = __floats2half2_rn(o.z, o.w);
        uint2 pk;
        pk.x = *(unsigned int*)&h01;
        pk.y = *(unsigned int*)&h23;
        ((uint2*)OutP)[(size_t)node * 32 + lane] = pk;
    } else {
        float p[10];
        const int c0 = lane * 4;
#pragma unroll
        for (int k = 0; k < 10; ++k) {
            p[k] = o.x * wlds[(c0 + 0) * 10 + k] + o.y * wlds[(c0 + 1) * 10 + k] +
                   o.z * wlds[(c0 + 2) * 10 + k] + o.w * wlds[(c0 + 3) * 10 + k];
        }
#pragma unroll
        for (int k = 0; k < 10; ++k) {
            float v = p[k];
            v += __shfl_xor(v, 1);
            v += __shfl_xor(v, 2);
            v += __shfl_xor(v, 4);
            v += __shfl_xor(v, 8);
            v += __shfl_xor(v, 16);
            p[k] = v;
        }
        if (lane == 0) {
            float* outp = (float*)OutP + (size_t)node * 10;
#pragma unroll
            for (int k = 0; k < 10; ++k) outp[k] = p[k] + bl[k];
        }
    }
}

// ---------------------------------------------------------------------------
extern "C" void kernel_launch(void* const* d_in, const int* in_sizes, int n_in,
                              void* d_out, int out_size, void* d_ws, size_t ws_size,
                              hipStream_t stream) {
    const float* x  = (const float*)d_in[0];
    const int*   ei = (const int*)d_in[1];
    const float* W1 = (const float*)d_in[2];
    const float* b1 = (const float*)d_in[3];
    const float* W2 = (const float*)d_in[4];
    const float* b2 = (const float*)d_in[5];
    const float* Wl = (const float*)d_in[6];
    const float* bl = (const float*)d_in[7];
    float* out = (float*)d_out;

    const int N = in_sizes[0] / C;   // 50000
    const int E = in_sizes[1] / 2;   // 800000
    const int* src = ei;
    const int* dst = ei + E;

    char* p = (char*)d_ws;
    _Float16* bufHs16 = (_Float16*)p;  p += (size_t)N * C * 2;
    _Float16* bufT16  = (_Float16*)p;  p += (size_t)N * C * 2;
    int*      cnt     = (int*)p;       p += (size_t)N * 4;
    int*      rowptr  = (int*)p;       p += (size_t)(N + 1) * 4;
    float*    dinv    = (float*)p;     p += (size_t)N * 4;
    int*      partials= (int*)p;       p += 1024;
    unsigned short* rank   = (unsigned short*)p;  p += (size_t)E * 2;
    unsigned short* colidx = (unsigned short*)p;

    const int gridN   = (N + 255) / 256;       // 196
    const int gridE   = (E + 255) / 256;       // 3125
    const int gridGemm = (N + 63) / 64;        // 782
    const int gridAgg = (N + 7) / 8;           // 6250

    // CSR build (once; shared by both layers)
    k_zero<<<gridN, 256, 0, stream>>>(cnt, N);
    k_histr<<<gridE, 256, 0, stream>>>(dst, cnt, rank, E);
    k_scan1<<<gridN, 256, 0, stream>>>(cnt, partials, N);
    k_scan2<<<1, 256, 0, stream>>>(partials, gridN);
    k_scan3<<<gridN, 256, 0, stream>>>(cnt, partials, rowptr, dinv, N, E);
    k_fill2<<<gridE, 256, 0, stream>>>(src, dst, rank, rowptr, colidx, E);

    // layer 1
    k_gemm_mfma<float><<<gridGemm, 256, 0, stream>>>(x, W1, dinv, bufHs16, N);
    k_aggf<0><<<gridAgg, 256, 0, stream>>>(bufHs16, rowptr, colidx, dinv,
                                           b1, nullptr, nullptr, bufT16, N);

    // layer 2
    k_gemm_mfma<_Float16><<<gridGemm, 256, 0, stream>>>(bufT16, W2, dinv, bufHs16, N);
    k_aggf<1><<<gridAgg, 256, 0, stream>>>(bufHs16, rowptr, colidx, dinv,
                                           b2, Wl, bl, out, N);
}